// Round 7
// baseline (339.934 us; speedup 1.0000x reference)
//
#include <hip/hip_runtime.h>
#include <hip/hip_bf16.h>
#include <math.h>

#define HID   1024
#define NHEAD 16
#define DHEAD 64
#define BATCH 2
#define SEQ   2048
#define TOK   (BATCH*SEQ)   // 4096

#define LOG2E_8 0.18033688011112042f   // log2(e)/8, folded into wq/bq

typedef float f32x4  __attribute__((ext_vector_type(4)));
typedef short short8 __attribute__((ext_vector_type(8)));

__device__ __forceinline__ unsigned short f2bf(float f) {
    unsigned int u = __float_as_uint(f);
    u += 0x7FFFu + ((u >> 16) & 1u);      // round-to-nearest-even
    return (unsigned short)(u >> 16);
}

__device__ __forceinline__ unsigned pk2(float lo, float hi) {
    union { __hip_bfloat162 h; unsigned u; } cv;
    cv.h = __float22bfloat162_rn(make_float2(lo, hi));
    return cv.u;
}

__device__ __forceinline__ float fexp2(float x) {
#if __has_builtin(__builtin_amdgcn_exp2f)
    return __builtin_amdgcn_exp2f(x);
#else
    return __expf(x * 0.6931471805599453f);
#endif
}

// async global->LDS, 16B per lane; lds dest = wave-uniform base + lane*16
__device__ __forceinline__ void gll16(const unsigned short* g, unsigned short* l) {
    __builtin_amdgcn_global_load_lds(
        (const __attribute__((address_space(1))) void*)g,
        (__attribute__((address_space(3))) void*)l, 16, 0, 0);
}

// ---------------------------------------------------------------------------
// fp32 -> bf16 convert, all 5 tensors in one launch (z: 0=x 1=wq 2=wk 3=wv 4=wo)
// wq scaled by log2(e)/8 so attention scores land in exp2 domain.
// ---------------------------------------------------------------------------
__global__ __launch_bounds__(256) void cvt_all(
    const float* __restrict__ x,  const float* __restrict__ wq,
    const float* __restrict__ wk, const float* __restrict__ wv,
    const float* __restrict__ wo,
    unsigned short* __restrict__ xb,  unsigned short* __restrict__ wqb,
    unsigned short* __restrict__ wkb, unsigned short* __restrict__ wvb,
    unsigned short* __restrict__ wob, int nx, int nw)
{
    const int i = blockIdx.x * 256 + threadIdx.x;
    const int z = blockIdx.y;
    const float* in; unsigned short* out; int n; float s = 1.0f;
    switch (z) {
        case 0:  in = x;  out = xb;  n = nx; break;
        case 1:  in = wq; out = wqb; n = nw; s = LOG2E_8; break;
        case 2:  in = wk; out = wkb; n = nw; break;
        case 3:  in = wv; out = wvb; n = nw; break;
        default: in = wo; out = wob; n = nw; break;
    }
    if (i >= n) return;
    const float4* p = (const float4*)in;
    float4 a = p[2*i], b = p[2*i+1];
    uint4 r;
    r.x = pk2(a.x*s, a.y*s); r.y = pk2(a.z*s, a.w*s);
    r.z = pk2(b.x*s, b.y*s); r.w = pk2(b.z*s, b.w*s);
    ((uint4*)out)[i] = r;
}

// ---------------------------------------------------------------------------
// bf16 MFMA GEMM (NT): C[M,N] = A[M,K]*W[N,K]^T + bias, templated tile.
// BM x BN tile, BK=32, 256 thr = 4 waves (2x2), wave-tile (BM/2)x(BN/2).
// global_load_lds width-16 staging, unpadded LDS with XOR-chunk swizzle.
// NZ=3: z picks (W,bias,C); z==0 bias scaled by LOG2E_8; z==2 writes V^T.
// ---------------------------------------------------------------------------
template<int BM, int BN, int NZ, bool OUTF32, int MINW>
__global__ __launch_bounds__(256, MINW) void gemm_t(
    const unsigned short* __restrict__ A,
    const unsigned short* __restrict__ W0, const unsigned short* __restrict__ W1,
    const unsigned short* __restrict__ W2,
    const float* __restrict__ b0, const float* __restrict__ b1, const float* __restrict__ b2,
    void* __restrict__ C0, void* __restrict__ C1, void* __restrict__ C2,
    int M, int N, int K)
{
    constexpr int MT = BM/32;      // m-tiles (16-wide) per wave
    constexpr int NT = BN/32;      // n-tiles per wave
    constexpr int AG = BM/64;      // gll16 per wave for A
    constexpr int WG = BN/64;      // gll16 per wave for W

    __shared__ unsigned short As[BM*32];
    __shared__ unsigned short Ws[BN*32];

    const unsigned short* W = W0; const float* bias = b0; void* C = C0;
    int z = 0;
    if (NZ > 1) {
        z = blockIdx.z;
        W    = (z==0) ? W0 : ((z==1) ? W1 : W2);
        bias = (z==0) ? b0 : ((z==1) ? b1 : b2);
        C    = (z==0) ? C0 : ((z==1) ? C1 : C2);
    }
    const int tid  = threadIdx.x;
    const int l15  = tid & 15, quad = (tid >> 4) & 3, w = tid >> 6;
    const int wm   = (w >> 1) * (BM/2), wn = (w & 1) * (BN/2);
    const int m0   = blockIdx.y * BM, n0 = blockIdx.x * BN;

    const int lane = tid & 63;
    const int grow = lane >> 2;
    const int gchk = (lane & 3) ^ (grow & 3);

    const unsigned short* pA[AG]; unsigned short* lA[AG];
    const unsigned short* pW[WG]; unsigned short* lW[WG];
    #pragma unroll
    for (int i = 0; i < AG; ++i) {
        const int r = w*(BM/4) + i*16;
        pA[i] = A + (size_t)(m0 + r + grow) * K + gchk*8;
        lA[i] = &As[r * 32];
    }
    #pragma unroll
    for (int i = 0; i < WG; ++i) {
        const int r = w*(BN/4) + i*16;
        pW[i] = W + (size_t)(n0 + r + grow) * K + gchk*8;
        lW[i] = &Ws[r * 32];
    }

    f32x4 acc[MT][NT] = {};

    for (int k0 = 0; k0 < K; k0 += 32) {
        #pragma unroll
        for (int i = 0; i < AG; ++i) { gll16(pA[i], lA[i]); pA[i] += 32; }
        #pragma unroll
        for (int i = 0; i < WG; ++i) { gll16(pW[i], lW[i]); pW[i] += 32; }
        __syncthreads();

        const int co = (quad ^ (l15 & 3)) * 8;
        short8 af[MT], bfv[NT];
        #pragma unroll
        for (int mi = 0; mi < MT; ++mi) af[mi]  = *(const short8*)&As[(wm + mi*16 + l15)*32 + co];
        #pragma unroll
        for (int ni = 0; ni < NT; ++ni) bfv[ni] = *(const short8*)&Ws[(wn + ni*16 + l15)*32 + co];
        #pragma unroll
        for (int mi = 0; mi < MT; ++mi)
            #pragma unroll
            for (int ni = 0; ni < NT; ++ni)
                acc[mi][ni] = __builtin_amdgcn_mfma_f32_16x16x32_bf16(af[mi], bfv[ni], acc[mi][ni], 0, 0, 0);
        __syncthreads();
    }

    const float bsc = (NZ == 3 && z == 0) ? LOG2E_8 : 1.0f;
    float bv[NT];
    #pragma unroll
    for (int ni = 0; ni < NT; ++ni) bv[ni] = bias[n0 + wn + ni*16 + l15] * bsc;

    if (NZ == 3 && z == 2) {
        // V output pre-transposed: vT[((b*16+h)*64+d)*SEQ + s], 4 seq packed
        #pragma unroll
        for (int mi = 0; mi < MT; ++mi)
            #pragma unroll
            for (int ni = 0; ni < NT; ++ni) {
                const int row0 = m0 + wm + mi*16 + quad*4;
                const int col  = n0 + wn + ni*16 + l15;
                const int hh = col >> 6, dd = col & 63;
                const int bb = row0 >> 11, ss = row0 & 2047;
                ushort4 r4;
                r4.x = f2bf(acc[mi][ni][0] + bv[ni]);
                r4.y = f2bf(acc[mi][ni][1] + bv[ni]);
                r4.z = f2bf(acc[mi][ni][2] + bv[ni]);
                r4.w = f2bf(acc[mi][ni][3] + bv[ni]);
                *(ushort4*)((unsigned short*)C + ((size_t)(bb*NHEAD + hh)*DHEAD + dd)*SEQ + ss) = r4;
            }
    } else {
        #pragma unroll
        for (int mi = 0; mi < MT; ++mi)
            #pragma unroll
            for (int ni = 0; ni < NT; ++ni)
                #pragma unroll
                for (int r = 0; r < 4; ++r) {
                    const int row = m0 + wm + mi*16 + quad*4 + r;
                    const int col = n0 + wn + ni*16 + l15;
                    const float val = acc[mi][ni][r] + bv[ni];
                    if (OUTF32) ((float*)C)[(size_t)row*N + col] = val;
                    else ((unsigned short*)C)[(size_t)row*N + col] = f2bf(val);
                }
    }
}

// ---------------------------------------------------------------------------
// bf16 MFMA flash attention v7 = v6 + double-buffered K/V with register
// prefetch (one barrier per tile; load latency hidden behind compute).
// S^T formulation, 4-way key split, 32-key tiles, Q-frags from global.
// Grid 8x16x8 = 1024 blocks = 4/CU. LDS = 2*4K + 2*4K + 16K = 32 KB.
// ---------------------------------------------------------------------------
__global__ __launch_bounds__(256, 4) void attn_v7(
    const unsigned short* __restrict__ Qg, const unsigned short* __restrict__ Kg,
    const unsigned short* __restrict__ vT,
    unsigned short* __restrict__ pO0, unsigned short* __restrict__ pO1,
    unsigned short* __restrict__ pO2, unsigned short* __restrict__ pO3,
    float* __restrict__ pl)
{
    __shared__ unsigned short Ks[2][32][64];     // [key][d]
    __shared__ unsigned short VT[2][64][32];     // [d][key]
    __shared__ unsigned short PT[4][64][32];     // per-wave P^T [q][key]

    const int tid  = threadIdx.x;
    const int l15  = tid & 15, quad = (tid >> 4) & 3, w = tid >> 6;
    const int z    = blockIdx.z;
    const int b    = z & 1, half = z >> 1;          // half 0..3
    const int h    = blockIdx.y;
    const int q0   = blockIdx.x * 256;
    const size_t rowbase = (size_t)b * SEQ;
    const int    cbase   = h * DHEAD;
    const size_t vbase   = (size_t)(b*NHEAD + h) * DHEAD * SEQ;
    const int    keybase = half * (SEQ/4);          // 512 keys per block

    // ---- Q B-frags straight from global (one-time, L2/L3-resident) ----
    short8 qa[4][2];
    #pragma unroll
    for (int nq = 0; nq < 4; ++nq)
        #pragma unroll
        for (int s2 = 0; s2 < 2; ++s2)
            qa[nq][s2] = *(const short8*)(Qg + (rowbase + q0 + w*64 + nq*16 + l15) * HID
                                             + cbase + s2*32 + quad*8);

    // ---- staging indices (one uint4 each for K and V per thread) ----
    const int kr_ = tid >> 3, kc_ = tid & 7;            // K: row=key, 8-elem d-chunk
    const int ksc = kc_ ^ (kr_ & 7);
    const int vd_ = tid >> 2, vkc = tid & 3;            // V: row=d, 8-elem key-chunk
    const int vsc = vkc ^ ((vd_ >> 1) & 3);
    const unsigned short* kgp = Kg + (rowbase + keybase + kr_) * HID + cbase + kc_*8;
    const unsigned short* vgp = vT + vbase + (size_t)vd_ * SEQ + keybase + vkc*8;

    // ---- prologue: stage tile 0 into buf 0 ----
    {
        const uint4 k0 = *(const uint4*)kgp;  kgp += (size_t)32 * HID;
        const uint4 v0 = *(const uint4*)vgp;  vgp += 32;
        *(uint4*)&Ks[0][kr_][ksc*8] = k0;
        *(uint4*)&VT[0][vd_][vsc*8] = v0;
    }

    f32x4 o[4][4] = {};
    float lsum[4] = {0.f, 0.f, 0.f, 0.f};
    const int fsw = (l15 >> 1) & 3;                     // frag swizzle base for VT/PT

    for (int kt = 0; kt < SEQ/4/32; ++kt) {             // 16 tiles of 32 keys
        const int buf = kt & 1;
        __syncthreads();                                // buf fully staged

        // ---- prefetch next tile into registers (in flight during compute) ----
        uint4 kn, vn;
        const bool pre = (kt + 1 < SEQ/4/32);
        if (pre) {
            kn = *(const uint4*)kgp;  kgp += (size_t)32 * HID;
            vn = *(const uint4*)vgp;  vgp += 32;
        }

        // ---- S^T = K . Q^T  (row=key(32), col=q(64)); log2-domain scores ----
        f32x4 s[2][4] = {};
        #pragma unroll
        for (int s2 = 0; s2 < 2; ++s2) {
            short8 kf[2];
            #pragma unroll
            for (int mi = 0; mi < 2; ++mi)
                kf[mi] = *(const short8*)&Ks[buf][mi*16 + l15][((((s2<<2)|quad)) ^ (l15 & 7)) * 8];
            #pragma unroll
            for (int mi = 0; mi < 2; ++mi)
                #pragma unroll
                for (int nq = 0; nq < 4; ++nq)
                    s[mi][nq] = __builtin_amdgcn_mfma_f32_16x16x32_bf16(kf[mi], qa[nq][s2], s[mi][nq], 0, 0, 0);
        }

        // ---- p = 2^s; accumulate l; uint2 P-writes ----
        #pragma unroll
        for (int mi = 0; mi < 2; ++mi)
            #pragma unroll
            for (int nq = 0; nq < 4; ++nq) {
                const float p0 = fexp2(s[mi][nq][0]);
                const float p1 = fexp2(s[mi][nq][1]);
                const float p2 = fexp2(s[mi][nq][2]);
                const float p3 = fexp2(s[mi][nq][3]);
                lsum[nq] += (p0 + p1) + (p2 + p3);
                uint2 u; u.x = pk2(p0, p1); u.y = pk2(p2, p3);
                const int sc = (2*mi + (quad >> 1)) ^ fsw;
                *(uint2*)&PT[w][nq*16 + l15][sc*8 + (quad & 1)*4] = u;
            }

        // ---- O^T += V^T . P^T  (PT wave-private: in-order, no barrier) ----
        short8 ptb[4], vf[4];
        #pragma unroll
        for (int nq = 0; nq < 4; ++nq)
            ptb[nq] = *(const short8*)&PT[w][nq*16 + l15][(quad ^ fsw) * 8];
        #pragma unroll
        for (int md = 0; md < 4; ++md)
            vf[md] = *(const short8*)&VT[buf][md*16 + l15][(quad ^ fsw) * 8];
        #pragma unroll
        for (int md = 0; md < 4; ++md)
            #pragma unroll
            for (int nq = 0; nq < 4; ++nq)
                o[md][nq] = __builtin_amdgcn_mfma_f32_16x16x32_bf16(vf[md], ptb[nq], o[md][nq], 0, 0, 0);

        // ---- write prefetched tile into the other buffer ----
        if (pre) {
            const int nb = buf ^ 1;
            *(uint4*)&Ks[nb][kr_][ksc*8] = kn;
            *(uint4*)&VT[nb][vd_][vsc*8] = vn;
        }
    }

    // ---- epilogue: un-normalized partial O (bf16) + l (fp32) ----
    unsigned short* pO = (half == 0) ? pO0 : ((half == 1) ? pO1 : ((half == 2) ? pO2 : pO3));
    #pragma unroll
    for (int nq = 0; nq < 4; ++nq) {
        float l = lsum[nq];
        l += __shfl_xor(l, 16);
        l += __shfl_xor(l, 32);
        if (quad == 0)
            pl[(((size_t)half * BATCH + b) * NHEAD + h) * SEQ + q0 + w*64 + nq*16 + l15] = l;
        const size_t row = rowbase + q0 + w*64 + nq*16 + l15;
        #pragma unroll
        for (int md = 0; md < 4; ++md) {
            ushort4 u;
            u.x = f2bf(o[md][nq][0]); u.y = f2bf(o[md][nq][1]);
            u.z = f2bf(o[md][nq][2]); u.w = f2bf(o[md][nq][3]);
            *(ushort4*)&pO[row * HID + cbase + md*16 + quad*4] = u;
        }
    }
}

// ---------------------------------------------------------------------------
// ctx = (p0+p1+p2+p3) / (l0+l1+l2+l3), bf16 out.
// ---------------------------------------------------------------------------
__device__ __forceinline__ unsigned addquad(unsigned a, unsigned b, unsigned c,
                                            unsigned d, float inv) {
    const float s0 = __uint_as_float(a << 16) + __uint_as_float(b << 16)
                   + __uint_as_float(c << 16) + __uint_as_float(d << 16);
    const float s1 = __uint_as_float(a & 0xffff0000u) + __uint_as_float(b & 0xffff0000u)
                   + __uint_as_float(c & 0xffff0000u) + __uint_as_float(d & 0xffff0000u);
    return pk2(s0 * inv, s1 * inv);
}

__global__ __launch_bounds__(256) void reduce4(
    const unsigned short* __restrict__ p0, const unsigned short* __restrict__ p1,
    const unsigned short* __restrict__ p2, const unsigned short* __restrict__ p3,
    const float* __restrict__ pl, unsigned short* __restrict__ ctx)
{
    const int i  = blockIdx.x * 256 + threadIdx.x;
    const int e0 = i * 8;
    const int t  = e0 >> 10;
    const int h  = (e0 & 1023) >> 6;
    const int b  = t >> 11, q = t & 2047;
    const size_t lb = ((size_t)b * NHEAD + h) * SEQ + q;
    const size_t lstep = (size_t)BATCH * NHEAD * SEQ;
    const float l = pl[lb] + pl[lb + lstep] + pl[lb + 2*lstep] + pl[lb + 3*lstep];
    const float inv = 1.f / l;
    uint4 a = ((const uint4*)p0)[i];
    uint4 b4 = ((const uint4*)p1)[i];
    uint4 c = ((const uint4*)p2)[i];
    uint4 d = ((const uint4*)p3)[i];
    uint4 r;
    r.x = addquad(a.x, b4.x, c.x, d.x, inv);
    r.y = addquad(a.y, b4.y, c.y, d.y, inv);
    r.z = addquad(a.z, b4.z, c.z, d.z, inv);
    r.w = addquad(a.w, b4.w, c.w, d.w, inv);
    ((uint4*)ctx)[i] = r;
}

// ---------------------------------------------------------------------------
extern "C" void kernel_launch(void* const* d_in, const int* in_sizes, int n_in,
                              void* d_out, int out_size, void* d_ws, size_t ws_size,
                              hipStream_t stream)
{
    const float* x  = (const float*)d_in[0];
    const float* wq = (const float*)d_in[1];
    const float* bq = (const float*)d_in[2];
    const float* wk = (const float*)d_in[3];
    const float* bk = (const float*)d_in[4];
    const float* wv = (const float*)d_in[5];
    const float* bv = (const float*)d_in[6];
    const float* wo = (const float*)d_in[7];
    const float* bo = (const float*)d_in[8];
    float* out = (float*)d_out;

    // ws layout (64 MB total)
    unsigned short* xb  = (unsigned short*)d_ws;       //  0- 8 MB  x bf16; then pO0
    unsigned short* wqb = xb  + (size_t)TOK * HID;     //  8-10 MB  wq; then pl (1 MB)
    unsigned short* wkb = wqb + (size_t)HID * HID;     // 10-12 MB
    unsigned short* wvb = wkb + (size_t)HID * HID;     // 12-14 MB
    unsigned short* wob = wvb + (size_t)HID * HID;     // 14-16 MB  (live to O-proj)
    unsigned short* qb  = wob + (size_t)HID * HID;     // 16-24 MB  Q; then ctx
    unsigned short* kb  = qb  + (size_t)TOK * HID;     // 24-32 MB  K
    unsigned short* vtb = kb  + (size_t)TOK * HID;     // 32-40 MB  V^T
    unsigned short* cb  = vtb + (size_t)TOK * HID;     // 40-48 MB  pO1
    unsigned short* cb2 = cb  + (size_t)TOK * HID;     // 48-56 MB  pO2
    unsigned short* cb3 = cb2 + (size_t)TOK * HID;     // 56-64 MB  pO3

    const dim3 blk(256);

    cvt_all<<<dim3(TOK*HID/8/256, 5), blk, 0, stream>>>(
        x, wq, wk, wv, wo, xb, wqb, wkb, wvb, wob, TOK*HID/8, HID*HID/8);

    // QKV: 128x128 tile, 768 blocks = 3/CU
    gemm_t<128, 128, 3, false, 3><<<dim3(HID/128, TOK/128, 3), blk, 0, stream>>>(
        xb, wqb, wkb, wvb, bq, bk, bv, qb, kb, vtb, TOK, HID, HID);

    // attention: 4-way key split, partials -> xb/cb/cb2/cb3, l -> wqb
    attn_v7<<<dim3(SEQ/256, NHEAD, BATCH*4), blk, 0, stream>>>(
        qb, kb, vtb, xb, cb, cb2, cb3, (float*)wqb);

    // recombine 4 partials -> ctx into qb (dead after attn)
    reduce4<<<dim3(TOK*HID/8/256), blk, 0, stream>>>(
        xb, cb, cb2, cb3, (float*)wqb, qb);

    // O-proj: 128x64 tile, 512 blocks = 2/CU
    gemm_t<128, 64, 1, true, 4><<<dim3(HID/64, TOK/128, 1), blk, 0, stream>>>(
        qb, wob, wob, wob, bo, bo, bo, out, out, out, TOK, HID, HID);
}

// Round 8
// 200.506 us; speedup vs baseline: 1.6954x; 1.6954x over previous
//
#include <hip/hip_runtime.h>
#include <hip/hip_bf16.h>
#include <math.h>

#define HID   1024
#define NHEAD 16
#define DHEAD 64
#define BATCH 2
#define SEQ   2048
#define TOK   (BATCH*SEQ)   // 4096

#define LOG2E_8 0.18033688011112042f   // log2(e)/8, folded into wq/bq

typedef float f32x4  __attribute__((ext_vector_type(4)));
typedef short short8 __attribute__((ext_vector_type(8)));

__device__ __forceinline__ unsigned short f2bf(float f) {
    unsigned int u = __float_as_uint(f);
    u += 0x7FFFu + ((u >> 16) & 1u);      // round-to-nearest-even
    return (unsigned short)(u >> 16);
}

__device__ __forceinline__ unsigned pk2(float lo, float hi) {
    union { __hip_bfloat162 h; unsigned u; } cv;
    cv.h = __float22bfloat162_rn(make_float2(lo, hi));
    return cv.u;
}

__device__ __forceinline__ float fexp2(float x) {
#if __has_builtin(__builtin_amdgcn_exp2f)
    return __builtin_amdgcn_exp2f(x);
#else
    return __expf(x * 0.6931471805599453f);
#endif
}

// async global->LDS, 16B per lane; lds dest = wave-uniform base + lane*16
__device__ __forceinline__ void gll16(const unsigned short* g, unsigned short* l) {
    __builtin_amdgcn_global_load_lds(
        (const __attribute__((address_space(1))) void*)g,
        (__attribute__((address_space(3))) void*)l, 16, 0, 0);
}

// ---------------------------------------------------------------------------
// fp32 -> bf16 convert, all 5 tensors in one launch (z: 0=x 1=wq 2=wk 3=wv 4=wo)
// wq scaled by log2(e)/8 so attention scores land in exp2 domain.
// ---------------------------------------------------------------------------
__global__ __launch_bounds__(256) void cvt_all(
    const float* __restrict__ x,  const float* __restrict__ wq,
    const float* __restrict__ wk, const float* __restrict__ wv,
    const float* __restrict__ wo,
    unsigned short* __restrict__ xb,  unsigned short* __restrict__ wqb,
    unsigned short* __restrict__ wkb, unsigned short* __restrict__ wvb,
    unsigned short* __restrict__ wob, int nx, int nw)
{
    const int i = blockIdx.x * 256 + threadIdx.x;
    const int z = blockIdx.y;
    const float* in; unsigned short* out; int n; float s = 1.0f;
    switch (z) {
        case 0:  in = x;  out = xb;  n = nx; break;
        case 1:  in = wq; out = wqb; n = nw; s = LOG2E_8; break;
        case 2:  in = wk; out = wkb; n = nw; break;
        case 3:  in = wv; out = wvb; n = nw; break;
        default: in = wo; out = wob; n = nw; break;
    }
    if (i >= n) return;
    const float4* p = (const float4*)in;
    float4 a = p[2*i], b = p[2*i+1];
    uint4 r;
    r.x = pk2(a.x*s, a.y*s); r.y = pk2(a.z*s, a.w*s);
    r.z = pk2(b.x*s, b.y*s); r.w = pk2(b.z*s, b.w*s);
    ((uint4*)out)[i] = r;
}

// ---------------------------------------------------------------------------
// bf16 MFMA GEMM (NT): C[M,N] = A[M,K]*W[N,K]^T + bias, templated tile.
// BM x BN tile, BK=32, 256 thr = 4 waves (2x2), wave-tile (BM/2)x(BN/2).
// global_load_lds width-16 staging, unpadded LDS with XOR-chunk swizzle.
// NZ=3: z picks (W,bias,C); z==0 bias scaled by LOG2E_8; z==2 writes V^T.
// ---------------------------------------------------------------------------
template<int BM, int BN, int NZ, bool OUTF32, int MINW>
__global__ __launch_bounds__(256, MINW) void gemm_t(
    const unsigned short* __restrict__ A,
    const unsigned short* __restrict__ W0, const unsigned short* __restrict__ W1,
    const unsigned short* __restrict__ W2,
    const float* __restrict__ b0, const float* __restrict__ b1, const float* __restrict__ b2,
    void* __restrict__ C0, void* __restrict__ C1, void* __restrict__ C2,
    int M, int N, int K)
{
    constexpr int MT = BM/32;      // m-tiles (16-wide) per wave
    constexpr int NT = BN/32;      // n-tiles per wave
    constexpr int AG = BM/64;      // gll16 per wave for A
    constexpr int WG = BN/64;      // gll16 per wave for W

    __shared__ unsigned short As[BM*32];
    __shared__ unsigned short Ws[BN*32];

    const unsigned short* W = W0; const float* bias = b0; void* C = C0;
    int z = 0;
    if (NZ > 1) {
        z = blockIdx.z;
        W    = (z==0) ? W0 : ((z==1) ? W1 : W2);
        bias = (z==0) ? b0 : ((z==1) ? b1 : b2);
        C    = (z==0) ? C0 : ((z==1) ? C1 : C2);
    }
    const int tid  = threadIdx.x;
    const int l15  = tid & 15, quad = (tid >> 4) & 3, w = tid >> 6;
    const int wm   = (w >> 1) * (BM/2), wn = (w & 1) * (BN/2);
    const int m0   = blockIdx.y * BM, n0 = blockIdx.x * BN;

    const int lane = tid & 63;
    const int grow = lane >> 2;
    const int gchk = (lane & 3) ^ (grow & 3);

    const unsigned short* pA[AG]; unsigned short* lA[AG];
    const unsigned short* pW[WG]; unsigned short* lW[WG];
    #pragma unroll
    for (int i = 0; i < AG; ++i) {
        const int r = w*(BM/4) + i*16;
        pA[i] = A + (size_t)(m0 + r + grow) * K + gchk*8;
        lA[i] = &As[r * 32];
    }
    #pragma unroll
    for (int i = 0; i < WG; ++i) {
        const int r = w*(BN/4) + i*16;
        pW[i] = W + (size_t)(n0 + r + grow) * K + gchk*8;
        lW[i] = &Ws[r * 32];
    }

    f32x4 acc[MT][NT] = {};

    for (int k0 = 0; k0 < K; k0 += 32) {
        #pragma unroll
        for (int i = 0; i < AG; ++i) { gll16(pA[i], lA[i]); pA[i] += 32; }
        #pragma unroll
        for (int i = 0; i < WG; ++i) { gll16(pW[i], lW[i]); pW[i] += 32; }
        __syncthreads();

        const int co = (quad ^ (l15 & 3)) * 8;
        short8 af[MT], bfv[NT];
        #pragma unroll
        for (int mi = 0; mi < MT; ++mi) af[mi]  = *(const short8*)&As[(wm + mi*16 + l15)*32 + co];
        #pragma unroll
        for (int ni = 0; ni < NT; ++ni) bfv[ni] = *(const short8*)&Ws[(wn + ni*16 + l15)*32 + co];
        #pragma unroll
        for (int mi = 0; mi < MT; ++mi)
            #pragma unroll
            for (int ni = 0; ni < NT; ++ni)
                acc[mi][ni] = __builtin_amdgcn_mfma_f32_16x16x32_bf16(af[mi], bfv[ni], acc[mi][ni], 0, 0, 0);
        __syncthreads();
    }

    const float bsc = (NZ == 3 && z == 0) ? LOG2E_8 : 1.0f;
    float bv[NT];
    #pragma unroll
    for (int ni = 0; ni < NT; ++ni) bv[ni] = bias[n0 + wn + ni*16 + l15] * bsc;

    if (NZ == 3 && z == 2) {
        // V output pre-transposed: vT[((b*16+h)*64+d)*SEQ + s], 4 seq packed
        #pragma unroll
        for (int mi = 0; mi < MT; ++mi)
            #pragma unroll
            for (int ni = 0; ni < NT; ++ni) {
                const int row0 = m0 + wm + mi*16 + quad*4;
                const int col  = n0 + wn + ni*16 + l15;
                const int hh = col >> 6, dd = col & 63;
                const int bb = row0 >> 11, ss = row0 & 2047;
                ushort4 r4;
                r4.x = f2bf(acc[mi][ni][0] + bv[ni]);
                r4.y = f2bf(acc[mi][ni][1] + bv[ni]);
                r4.z = f2bf(acc[mi][ni][2] + bv[ni]);
                r4.w = f2bf(acc[mi][ni][3] + bv[ni]);
                *(ushort4*)((unsigned short*)C + ((size_t)(bb*NHEAD + hh)*DHEAD + dd)*SEQ + ss) = r4;
            }
    } else {
        #pragma unroll
        for (int mi = 0; mi < MT; ++mi)
            #pragma unroll
            for (int ni = 0; ni < NT; ++ni)
                #pragma unroll
                for (int r = 0; r < 4; ++r) {
                    const int row = m0 + wm + mi*16 + quad*4 + r;
                    const int col = n0 + wn + ni*16 + l15;
                    const float val = acc[mi][ni][r] + bv[ni];
                    if (OUTF32) ((float*)C)[(size_t)row*N + col] = val;
                    else ((unsigned short*)C)[(size_t)row*N + col] = f2bf(val);
                }
    }
}

// ---------------------------------------------------------------------------
// bf16 MFMA flash attention v8 = v7 with launch_bounds(256,3).
// R7's (256,4) clamped VGPRs to 64 -> the 64-reg accumulator spilled to
// scratch (834 MB HBM traffic). (256,3) caps ~170; v6 compiled to 84 here.
// Double-buffered K/V + register prefetch, one barrier per tile.
// Grid 8x16x8 = 1024 blocks = 4/CU. LDS = 2*4K + 2*4K + 16K = 32 KB.
// ---------------------------------------------------------------------------
__global__ __launch_bounds__(256, 3) void attn_v8(
    const unsigned short* __restrict__ Qg, const unsigned short* __restrict__ Kg,
    const unsigned short* __restrict__ vT,
    unsigned short* __restrict__ pO0, unsigned short* __restrict__ pO1,
    unsigned short* __restrict__ pO2, unsigned short* __restrict__ pO3,
    float* __restrict__ pl)
{
    __shared__ unsigned short Ks[2][32][64];     // [key][d]
    __shared__ unsigned short VT[2][64][32];     // [d][key]
    __shared__ unsigned short PT[4][64][32];     // per-wave P^T [q][key]

    const int tid  = threadIdx.x;
    const int l15  = tid & 15, quad = (tid >> 4) & 3, w = tid >> 6;
    const int z    = blockIdx.z;
    const int b    = z & 1, half = z >> 1;          // half 0..3
    const int h    = blockIdx.y;
    const int q0   = blockIdx.x * 256;
    const size_t rowbase = (size_t)b * SEQ;
    const int    cbase   = h * DHEAD;
    const size_t vbase   = (size_t)(b*NHEAD + h) * DHEAD * SEQ;
    const int    keybase = half * (SEQ/4);          // 512 keys per block

    // ---- Q B-frags straight from global (one-time, L2/L3-resident) ----
    short8 qa[4][2];
    #pragma unroll
    for (int nq = 0; nq < 4; ++nq)
        #pragma unroll
        for (int s2 = 0; s2 < 2; ++s2)
            qa[nq][s2] = *(const short8*)(Qg + (rowbase + q0 + w*64 + nq*16 + l15) * HID
                                             + cbase + s2*32 + quad*8);

    // ---- staging indices (one uint4 each for K and V per thread) ----
    const int kr_ = tid >> 3, kc_ = tid & 7;            // K: row=key, 8-elem d-chunk
    const int ksc = kc_ ^ (kr_ & 7);
    const int vd_ = tid >> 2, vkc = tid & 3;            // V: row=d, 8-elem key-chunk
    const int vsc = vkc ^ ((vd_ >> 1) & 3);
    const unsigned short* kgp = Kg + (rowbase + keybase + kr_) * HID + cbase + kc_*8;
    const unsigned short* vgp = vT + vbase + (size_t)vd_ * SEQ + keybase + vkc*8;

    // ---- prologue: stage tile 0 into buf 0 ----
    {
        const uint4 k0 = *(const uint4*)kgp;  kgp += (size_t)32 * HID;
        const uint4 v0 = *(const uint4*)vgp;  vgp += 32;
        *(uint4*)&Ks[0][kr_][ksc*8] = k0;
        *(uint4*)&VT[0][vd_][vsc*8] = v0;
    }

    f32x4 o[4][4] = {};
    float lsum[4] = {0.f, 0.f, 0.f, 0.f};
    const int fsw = (l15 >> 1) & 3;                     // frag swizzle base for VT/PT

    for (int kt = 0; kt < SEQ/4/32; ++kt) {             // 16 tiles of 32 keys
        const int buf = kt & 1;
        __syncthreads();                                // buf fully staged

        // ---- prefetch next tile into registers (in flight during compute) ----
        uint4 kn, vn;
        const bool pre = (kt + 1 < SEQ/4/32);
        if (pre) {
            kn = *(const uint4*)kgp;  kgp += (size_t)32 * HID;
            vn = *(const uint4*)vgp;  vgp += 32;
        }

        // ---- S^T = K . Q^T  (row=key(32), col=q(64)); log2-domain scores ----
        f32x4 s[2][4] = {};
        #pragma unroll
        for (int s2 = 0; s2 < 2; ++s2) {
            short8 kf[2];
            #pragma unroll
            for (int mi = 0; mi < 2; ++mi)
                kf[mi] = *(const short8*)&Ks[buf][mi*16 + l15][((((s2<<2)|quad)) ^ (l15 & 7)) * 8];
            #pragma unroll
            for (int mi = 0; mi < 2; ++mi)
                #pragma unroll
                for (int nq = 0; nq < 4; ++nq)
                    s[mi][nq] = __builtin_amdgcn_mfma_f32_16x16x32_bf16(kf[mi], qa[nq][s2], s[mi][nq], 0, 0, 0);
        }

        // ---- p = 2^s; accumulate l; uint2 P-writes ----
        #pragma unroll
        for (int mi = 0; mi < 2; ++mi)
            #pragma unroll
            for (int nq = 0; nq < 4; ++nq) {
                const float p0 = fexp2(s[mi][nq][0]);
                const float p1 = fexp2(s[mi][nq][1]);
                const float p2 = fexp2(s[mi][nq][2]);
                const float p3 = fexp2(s[mi][nq][3]);
                lsum[nq] += (p0 + p1) + (p2 + p3);
                uint2 u; u.x = pk2(p0, p1); u.y = pk2(p2, p3);
                const int sc = (2*mi + (quad >> 1)) ^ fsw;
                *(uint2*)&PT[w][nq*16 + l15][sc*8 + (quad & 1)*4] = u;
            }

        // ---- O^T += V^T . P^T  (PT wave-private: in-order, no barrier) ----
        short8 ptb[4], vf[4];
        #pragma unroll
        for (int nq = 0; nq < 4; ++nq)
            ptb[nq] = *(const short8*)&PT[w][nq*16 + l15][(quad ^ fsw) * 8];
        #pragma unroll
        for (int md = 0; md < 4; ++md)
            vf[md] = *(const short8*)&VT[buf][md*16 + l15][(quad ^ fsw) * 8];
        #pragma unroll
        for (int md = 0; md < 4; ++md)
            #pragma unroll
            for (int nq = 0; nq < 4; ++nq)
                o[md][nq] = __builtin_amdgcn_mfma_f32_16x16x32_bf16(vf[md], ptb[nq], o[md][nq], 0, 0, 0);

        // ---- write prefetched tile into the other buffer ----
        if (pre) {
            const int nb = buf ^ 1;
            *(uint4*)&Ks[nb][kr_][ksc*8] = kn;
            *(uint4*)&VT[nb][vd_][vsc*8] = vn;
        }
    }

    // ---- epilogue: un-normalized partial O (bf16) + l (fp32) ----
    unsigned short* pO = (half == 0) ? pO0 : ((half == 1) ? pO1 : ((half == 2) ? pO2 : pO3));
    #pragma unroll
    for (int nq = 0; nq < 4; ++nq) {
        float l = lsum[nq];
        l += __shfl_xor(l, 16);
        l += __shfl_xor(l, 32);
        if (quad == 0)
            pl[(((size_t)half * BATCH + b) * NHEAD + h) * SEQ + q0 + w*64 + nq*16 + l15] = l;
        const size_t row = rowbase + q0 + w*64 + nq*16 + l15;
        #pragma unroll
        for (int md = 0; md < 4; ++md) {
            ushort4 u;
            u.x = f2bf(o[md][nq][0]); u.y = f2bf(o[md][nq][1]);
            u.z = f2bf(o[md][nq][2]); u.w = f2bf(o[md][nq][3]);
            *(ushort4*)&pO[row * HID + cbase + md*16 + quad*4] = u;
        }
    }
}

// ---------------------------------------------------------------------------
// ctx = (p0+p1+p2+p3) / (l0+l1+l2+l3), bf16 out.
// ---------------------------------------------------------------------------
__device__ __forceinline__ unsigned addquad(unsigned a, unsigned b, unsigned c,
                                            unsigned d, float inv) {
    const float s0 = __uint_as_float(a << 16) + __uint_as_float(b << 16)
                   + __uint_as_float(c << 16) + __uint_as_float(d << 16);
    const float s1 = __uint_as_float(a & 0xffff0000u) + __uint_as_float(b & 0xffff0000u)
                   + __uint_as_float(c & 0xffff0000u) + __uint_as_float(d & 0xffff0000u);
    return pk2(s0 * inv, s1 * inv);
}

__global__ __launch_bounds__(256) void reduce4(
    const unsigned short* __restrict__ p0, const unsigned short* __restrict__ p1,
    const unsigned short* __restrict__ p2, const unsigned short* __restrict__ p3,
    const float* __restrict__ pl, unsigned short* __restrict__ ctx)
{
    const int i  = blockIdx.x * 256 + threadIdx.x;
    const int e0 = i * 8;
    const int t  = e0 >> 10;
    const int h  = (e0 & 1023) >> 6;
    const int b  = t >> 11, q = t & 2047;
    const size_t lb = ((size_t)b * NHEAD + h) * SEQ + q;
    const size_t lstep = (size_t)BATCH * NHEAD * SEQ;
    const float l = pl[lb] + pl[lb + lstep] + pl[lb + 2*lstep] + pl[lb + 3*lstep];
    const float inv = 1.f / l;
    uint4 a = ((const uint4*)p0)[i];
    uint4 b4 = ((const uint4*)p1)[i];
    uint4 c = ((const uint4*)p2)[i];
    uint4 d = ((const uint4*)p3)[i];
    uint4 r;
    r.x = addquad(a.x, b4.x, c.x, d.x, inv);
    r.y = addquad(a.y, b4.y, c.y, d.y, inv);
    r.z = addquad(a.z, b4.z, c.z, d.z, inv);
    r.w = addquad(a.w, b4.w, c.w, d.w, inv);
    ((uint4*)ctx)[i] = r;
}

// ---------------------------------------------------------------------------
extern "C" void kernel_launch(void* const* d_in, const int* in_sizes, int n_in,
                              void* d_out, int out_size, void* d_ws, size_t ws_size,
                              hipStream_t stream)
{
    const float* x  = (const float*)d_in[0];
    const float* wq = (const float*)d_in[1];
    const float* bq = (const float*)d_in[2];
    const float* wk = (const float*)d_in[3];
    const float* bk = (const float*)d_in[4];
    const float* wv = (const float*)d_in[5];
    const float* bv = (const float*)d_in[6];
    const float* wo = (const float*)d_in[7];
    const float* bo = (const float*)d_in[8];
    float* out = (float*)d_out;

    // ws layout (64 MB total)
    unsigned short* xb  = (unsigned short*)d_ws;       //  0- 8 MB  x bf16; then pO0
    unsigned short* wqb = xb  + (size_t)TOK * HID;     //  8-10 MB  wq; then pl (1 MB)
    unsigned short* wkb = wqb + (size_t)HID * HID;     // 10-12 MB
    unsigned short* wvb = wkb + (size_t)HID * HID;     // 12-14 MB
    unsigned short* wob = wvb + (size_t)HID * HID;     // 14-16 MB  (live to O-proj)
    unsigned short* qb  = wob + (size_t)HID * HID;     // 16-24 MB  Q; then ctx
    unsigned short* kb  = qb  + (size_t)TOK * HID;     // 24-32 MB  K
    unsigned short* vtb = kb  + (size_t)TOK * HID;     // 32-40 MB  V^T
    unsigned short* cb  = vtb + (size_t)TOK * HID;     // 40-48 MB  pO1
    unsigned short* cb2 = cb  + (size_t)TOK * HID;     // 48-56 MB  pO2
    unsigned short* cb3 = cb2 + (size_t)TOK * HID;     // 56-64 MB  pO3

    const dim3 blk(256);

    cvt_all<<<dim3(TOK*HID/8/256, 5), blk, 0, stream>>>(
        x, wq, wk, wv, wo, xb, wqb, wkb, wvb, wob, TOK*HID/8, HID*HID/8);

    // QKV: 128x128 tile, 768 blocks = 3/CU
    gemm_t<128, 128, 3, false, 3><<<dim3(HID/128, TOK/128, 3), blk, 0, stream>>>(
        xb, wqb, wkb, wvb, bq, bk, bv, qb, kb, vtb, TOK, HID, HID);

    // attention: 4-way key split, partials -> xb/cb/cb2/cb3, l -> wqb
    attn_v8<<<dim3(SEQ/256, NHEAD, BATCH*4), blk, 0, stream>>>(
        qb, kb, vtb, xb, cb, cb2, cb3, (float*)wqb);

    // recombine 4 partials -> ctx into qb (dead after attn)
    reduce4<<<dim3(TOK*HID/8/256), blk, 0, stream>>>(
        xb, cb, cb2, cb3, (float*)wqb, qb);

    // O-proj: 128x64 tile, 512 blocks = 2/CU
    gemm_t<128, 64, 1, true, 4><<<dim3(HID/64, TOK/128, 1), blk, 0, stream>>>(
        qb, wob, wob, wob, bo, bo, bo, out, out, out, TOK, HID, HID);
}

// Round 9
// 196.021 us; speedup vs baseline: 1.7342x; 1.0229x over previous
//
#include <hip/hip_runtime.h>
#include <hip/hip_bf16.h>
#include <math.h>

#define HID   1024
#define NHEAD 16
#define DHEAD 64
#define BATCH 2
#define SEQ   2048
#define TOK   (BATCH*SEQ)   // 4096

#define LOG2E_8 0.18033688011112042f   // log2(e)/8, folded into wq/bq

typedef float f32x4  __attribute__((ext_vector_type(4)));
typedef short short8 __attribute__((ext_vector_type(8)));

__device__ __forceinline__ unsigned short f2bf(float f) {
    unsigned int u = __float_as_uint(f);
    u += 0x7FFFu + ((u >> 16) & 1u);      // round-to-nearest-even
    return (unsigned short)(u >> 16);
}

__device__ __forceinline__ unsigned pk2(float lo, float hi) {
    union { __hip_bfloat162 h; unsigned u; } cv;
    cv.h = __float22bfloat162_rn(make_float2(lo, hi));
    return cv.u;
}

__device__ __forceinline__ float fexp2(float x) {
#if __has_builtin(__builtin_amdgcn_exp2f)
    return __builtin_amdgcn_exp2f(x);
#else
    return __expf(x * 0.6931471805599453f);
#endif
}

// async global->LDS, 16B per lane; lds dest = wave-uniform base + lane*16
__device__ __forceinline__ void gll16(const unsigned short* g, unsigned short* l) {
    __builtin_amdgcn_global_load_lds(
        (const __attribute__((address_space(1))) void*)g,
        (__attribute__((address_space(3))) void*)l, 16, 0, 0);
}

// ---------------------------------------------------------------------------
// fp32 -> bf16 convert, all 5 tensors in one launch (z: 0=x 1=wq 2=wk 3=wv 4=wo)
// wq scaled by log2(e)/8 so attention scores land in exp2 domain.
// ---------------------------------------------------------------------------
__global__ __launch_bounds__(256) void cvt_all(
    const float* __restrict__ x,  const float* __restrict__ wq,
    const float* __restrict__ wk, const float* __restrict__ wv,
    const float* __restrict__ wo,
    unsigned short* __restrict__ xb,  unsigned short* __restrict__ wqb,
    unsigned short* __restrict__ wkb, unsigned short* __restrict__ wvb,
    unsigned short* __restrict__ wob, int nx, int nw)
{
    const int i = blockIdx.x * 256 + threadIdx.x;
    const int z = blockIdx.y;
    const float* in; unsigned short* out; int n; float s = 1.0f;
    switch (z) {
        case 0:  in = x;  out = xb;  n = nx; break;
        case 1:  in = wq; out = wqb; n = nw; s = LOG2E_8; break;
        case 2:  in = wk; out = wkb; n = nw; break;
        case 3:  in = wv; out = wvb; n = nw; break;
        default: in = wo; out = wob; n = nw; break;
    }
    if (i >= n) return;
    const float4* p = (const float4*)in;
    float4 a = p[2*i], b = p[2*i+1];
    uint4 r;
    r.x = pk2(a.x*s, a.y*s); r.y = pk2(a.z*s, a.w*s);
    r.z = pk2(b.x*s, b.y*s); r.w = pk2(b.z*s, b.w*s);
    ((uint4*)out)[i] = r;
}

// ---------------------------------------------------------------------------
// bf16 MFMA GEMM (NT): C[M,N] = A[M,K]*W[N,K]^T + bias, templated tile.
// BM x BN tile, BK=32, 256 thr = 4 waves (2x2), wave-tile (BM/2)x(BN/2).
// global_load_lds width-16 staging, unpadded LDS with XOR-chunk swizzle.
// NZ=3: z picks (W,bias,C); z==0 bias scaled by LOG2E_8; z==2 writes V^T.
// ---------------------------------------------------------------------------
template<int BM, int BN, int NZ, bool OUTF32, int MINW>
__global__ __launch_bounds__(256, MINW) void gemm_t(
    const unsigned short* __restrict__ A,
    const unsigned short* __restrict__ W0, const unsigned short* __restrict__ W1,
    const unsigned short* __restrict__ W2,
    const float* __restrict__ b0, const float* __restrict__ b1, const float* __restrict__ b2,
    void* __restrict__ C0, void* __restrict__ C1, void* __restrict__ C2,
    int M, int N, int K)
{
    constexpr int MT = BM/32;      // m-tiles (16-wide) per wave
    constexpr int NT = BN/32;      // n-tiles per wave
    constexpr int AG = BM/64;      // gll16 per wave for A
    constexpr int WG = BN/64;      // gll16 per wave for W

    __shared__ unsigned short As[BM*32];
    __shared__ unsigned short Ws[BN*32];

    const unsigned short* W = W0; const float* bias = b0; void* C = C0;
    int z = 0;
    if (NZ > 1) {
        z = blockIdx.z;
        W    = (z==0) ? W0 : ((z==1) ? W1 : W2);
        bias = (z==0) ? b0 : ((z==1) ? b1 : b2);
        C    = (z==0) ? C0 : ((z==1) ? C1 : C2);
    }
    const int tid  = threadIdx.x;
    const int l15  = tid & 15, quad = (tid >> 4) & 3, w = tid >> 6;
    const int wm   = (w >> 1) * (BM/2), wn = (w & 1) * (BN/2);
    const int m0   = blockIdx.y * BM, n0 = blockIdx.x * BN;

    const int lane = tid & 63;
    const int grow = lane >> 2;
    const int gchk = (lane & 3) ^ (grow & 3);

    const unsigned short* pA[AG]; unsigned short* lA[AG];
    const unsigned short* pW[WG]; unsigned short* lW[WG];
    #pragma unroll
    for (int i = 0; i < AG; ++i) {
        const int r = w*(BM/4) + i*16;
        pA[i] = A + (size_t)(m0 + r + grow) * K + gchk*8;
        lA[i] = &As[r * 32];
    }
    #pragma unroll
    for (int i = 0; i < WG; ++i) {
        const int r = w*(BN/4) + i*16;
        pW[i] = W + (size_t)(n0 + r + grow) * K + gchk*8;
        lW[i] = &Ws[r * 32];
    }

    f32x4 acc[MT][NT] = {};

    for (int k0 = 0; k0 < K; k0 += 32) {
        #pragma unroll
        for (int i = 0; i < AG; ++i) { gll16(pA[i], lA[i]); pA[i] += 32; }
        #pragma unroll
        for (int i = 0; i < WG; ++i) { gll16(pW[i], lW[i]); pW[i] += 32; }
        __syncthreads();

        const int co = (quad ^ (l15 & 3)) * 8;
        short8 af[MT], bfv[NT];
        #pragma unroll
        for (int mi = 0; mi < MT; ++mi) af[mi]  = *(const short8*)&As[(wm + mi*16 + l15)*32 + co];
        #pragma unroll
        for (int ni = 0; ni < NT; ++ni) bfv[ni] = *(const short8*)&Ws[(wn + ni*16 + l15)*32 + co];
        #pragma unroll
        for (int mi = 0; mi < MT; ++mi)
            #pragma unroll
            for (int ni = 0; ni < NT; ++ni)
                acc[mi][ni] = __builtin_amdgcn_mfma_f32_16x16x32_bf16(af[mi], bfv[ni], acc[mi][ni], 0, 0, 0);
        __syncthreads();
    }

    const float bsc = (NZ == 3 && z == 0) ? LOG2E_8 : 1.0f;
    float bv[NT];
    #pragma unroll
    for (int ni = 0; ni < NT; ++ni) bv[ni] = bias[n0 + wn + ni*16 + l15] * bsc;

    if (NZ == 3 && z == 2) {
        // V output pre-transposed: vT[((b*16+h)*64+d)*SEQ + s], 4 seq packed
        #pragma unroll
        for (int mi = 0; mi < MT; ++mi)
            #pragma unroll
            for (int ni = 0; ni < NT; ++ni) {
                const int row0 = m0 + wm + mi*16 + quad*4;
                const int col  = n0 + wn + ni*16 + l15;
                const int hh = col >> 6, dd = col & 63;
                const int bb = row0 >> 11, ss = row0 & 2047;
                ushort4 r4;
                r4.x = f2bf(acc[mi][ni][0] + bv[ni]);
                r4.y = f2bf(acc[mi][ni][1] + bv[ni]);
                r4.z = f2bf(acc[mi][ni][2] + bv[ni]);
                r4.w = f2bf(acc[mi][ni][3] + bv[ni]);
                *(ushort4*)((unsigned short*)C + ((size_t)(bb*NHEAD + hh)*DHEAD + dd)*SEQ + ss) = r4;
            }
    } else {
        #pragma unroll
        for (int mi = 0; mi < MT; ++mi)
            #pragma unroll
            for (int ni = 0; ni < NT; ++ni)
                #pragma unroll
                for (int r = 0; r < 4; ++r) {
                    const int row = m0 + wm + mi*16 + quad*4 + r;
                    const int col = n0 + wn + ni*16 + l15;
                    const float val = acc[mi][ni][r] + bv[ni];
                    if (OUTF32) ((float*)C)[(size_t)row*N + col] = val;
                    else ((unsigned short*)C)[(size_t)row*N + col] = f2bf(val);
                }
    }
}

// ---------------------------------------------------------------------------
// bf16 MFMA flash attention (= R8's attn_v8, unchanged).
// Double-buffered K/V + register prefetch, one barrier per tile.
// Grid 8x16x8 = 1024 blocks = 4/CU. LDS = 2*4K + 2*4K + 16K = 32 KB.
// launch_bounds(256,3): VGPR 84, no spill (R7's (256,4) spilled the acc).
// ---------------------------------------------------------------------------
__global__ __launch_bounds__(256, 3) void attn_v8(
    const unsigned short* __restrict__ Qg, const unsigned short* __restrict__ Kg,
    const unsigned short* __restrict__ vT,
    unsigned short* __restrict__ pO0, unsigned short* __restrict__ pO1,
    unsigned short* __restrict__ pO2, unsigned short* __restrict__ pO3,
    float* __restrict__ pl)
{
    __shared__ unsigned short Ks[2][32][64];     // [key][d]
    __shared__ unsigned short VT[2][64][32];     // [d][key]
    __shared__ unsigned short PT[4][64][32];     // per-wave P^T [q][key]

    const int tid  = threadIdx.x;
    const int l15  = tid & 15, quad = (tid >> 4) & 3, w = tid >> 6;
    const int z    = blockIdx.z;
    const int b    = z & 1, half = z >> 1;          // half 0..3
    const int h    = blockIdx.y;
    const int q0   = blockIdx.x * 256;
    const size_t rowbase = (size_t)b * SEQ;
    const int    cbase   = h * DHEAD;
    const size_t vbase   = (size_t)(b*NHEAD + h) * DHEAD * SEQ;
    const int    keybase = half * (SEQ/4);          // 512 keys per block

    // ---- Q B-frags straight from global (one-time, L2/L3-resident) ----
    short8 qa[4][2];
    #pragma unroll
    for (int nq = 0; nq < 4; ++nq)
        #pragma unroll
        for (int s2 = 0; s2 < 2; ++s2)
            qa[nq][s2] = *(const short8*)(Qg + (rowbase + q0 + w*64 + nq*16 + l15) * HID
                                             + cbase + s2*32 + quad*8);

    // ---- staging indices (one uint4 each for K and V per thread) ----
    const int kr_ = tid >> 3, kc_ = tid & 7;            // K: row=key, 8-elem d-chunk
    const int ksc = kc_ ^ (kr_ & 7);
    const int vd_ = tid >> 2, vkc = tid & 3;            // V: row=d, 8-elem key-chunk
    const int vsc = vkc ^ ((vd_ >> 1) & 3);
    const unsigned short* kgp = Kg + (rowbase + keybase + kr_) * HID + cbase + kc_*8;
    const unsigned short* vgp = vT + vbase + (size_t)vd_ * SEQ + keybase + vkc*8;

    // ---- prologue: stage tile 0 into buf 0 ----
    {
        const uint4 k0 = *(const uint4*)kgp;  kgp += (size_t)32 * HID;
        const uint4 v0 = *(const uint4*)vgp;  vgp += 32;
        *(uint4*)&Ks[0][kr_][ksc*8] = k0;
        *(uint4*)&VT[0][vd_][vsc*8] = v0;
    }

    f32x4 o[4][4] = {};
    float lsum[4] = {0.f, 0.f, 0.f, 0.f};
    const int fsw = (l15 >> 1) & 3;                     // frag swizzle base for VT/PT

    for (int kt = 0; kt < SEQ/4/32; ++kt) {             // 16 tiles of 32 keys
        const int buf = kt & 1;
        __syncthreads();                                // buf fully staged

        // ---- prefetch next tile into registers (in flight during compute) ----
        uint4 kn, vn;
        const bool pre = (kt + 1 < SEQ/4/32);
        if (pre) {
            kn = *(const uint4*)kgp;  kgp += (size_t)32 * HID;
            vn = *(const uint4*)vgp;  vgp += 32;
        }

        // ---- S^T = K . Q^T  (row=key(32), col=q(64)); log2-domain scores ----
        f32x4 s[2][4] = {};
        #pragma unroll
        for (int s2 = 0; s2 < 2; ++s2) {
            short8 kf[2];
            #pragma unroll
            for (int mi = 0; mi < 2; ++mi)
                kf[mi] = *(const short8*)&Ks[buf][mi*16 + l15][((((s2<<2)|quad)) ^ (l15 & 7)) * 8];
            #pragma unroll
            for (int mi = 0; mi < 2; ++mi)
                #pragma unroll
                for (int nq = 0; nq < 4; ++nq)
                    s[mi][nq] = __builtin_amdgcn_mfma_f32_16x16x32_bf16(kf[mi], qa[nq][s2], s[mi][nq], 0, 0, 0);
        }

        // ---- p = 2^s; accumulate l; uint2 P-writes ----
        #pragma unroll
        for (int mi = 0; mi < 2; ++mi)
            #pragma unroll
            for (int nq = 0; nq < 4; ++nq) {
                const float p0 = fexp2(s[mi][nq][0]);
                const float p1 = fexp2(s[mi][nq][1]);
                const float p2 = fexp2(s[mi][nq][2]);
                const float p3 = fexp2(s[mi][nq][3]);
                lsum[nq] += (p0 + p1) + (p2 + p3);
                uint2 u; u.x = pk2(p0, p1); u.y = pk2(p2, p3);
                const int sc = (2*mi + (quad >> 1)) ^ fsw;
                *(uint2*)&PT[w][nq*16 + l15][sc*8 + (quad & 1)*4] = u;
            }

        // ---- O^T += V^T . P^T  (PT wave-private: in-order, no barrier) ----
        short8 ptb[4], vf[4];
        #pragma unroll
        for (int nq = 0; nq < 4; ++nq)
            ptb[nq] = *(const short8*)&PT[w][nq*16 + l15][(quad ^ fsw) * 8];
        #pragma unroll
        for (int md = 0; md < 4; ++md)
            vf[md] = *(const short8*)&VT[buf][md*16 + l15][(quad ^ fsw) * 8];
        #pragma unroll
        for (int md = 0; md < 4; ++md)
            #pragma unroll
            for (int nq = 0; nq < 4; ++nq)
                o[md][nq] = __builtin_amdgcn_mfma_f32_16x16x32_bf16(vf[md], ptb[nq], o[md][nq], 0, 0, 0);

        // ---- write prefetched tile into the other buffer ----
        if (pre) {
            const int nb = buf ^ 1;
            *(uint4*)&Ks[nb][kr_][ksc*8] = kn;
            *(uint4*)&VT[nb][vd_][vsc*8] = vn;
        }
    }

    // ---- epilogue: un-normalized partial O (bf16) + l (fp32) ----
    unsigned short* pO = (half == 0) ? pO0 : ((half == 1) ? pO1 : ((half == 2) ? pO2 : pO3));
    #pragma unroll
    for (int nq = 0; nq < 4; ++nq) {
        float l = lsum[nq];
        l += __shfl_xor(l, 16);
        l += __shfl_xor(l, 32);
        if (quad == 0)
            pl[(((size_t)half * BATCH + b) * NHEAD + h) * SEQ + q0 + w*64 + nq*16 + l15] = l;
        const size_t row = rowbase + q0 + w*64 + nq*16 + l15;
        #pragma unroll
        for (int md = 0; md < 4; ++md) {
            ushort4 u;
            u.x = f2bf(o[md][nq][0]); u.y = f2bf(o[md][nq][1]);
            u.z = f2bf(o[md][nq][2]); u.w = f2bf(o[md][nq][3]);
            *(ushort4*)&pO[row * HID + cbase + md*16 + quad*4] = u;
        }
    }
}

// ---------------------------------------------------------------------------
// ctx = (p0+p1+p2+p3) / (l0+l1+l2+l3), bf16 out.
// ---------------------------------------------------------------------------
__device__ __forceinline__ unsigned addquad(unsigned a, unsigned b, unsigned c,
                                            unsigned d, float inv) {
    const float s0 = __uint_as_float(a << 16) + __uint_as_float(b << 16)
                   + __uint_as_float(c << 16) + __uint_as_float(d << 16);
    const float s1 = __uint_as_float(a & 0xffff0000u) + __uint_as_float(b & 0xffff0000u)
                   + __uint_as_float(c & 0xffff0000u) + __uint_as_float(d & 0xffff0000u);
    return pk2(s0 * inv, s1 * inv);
}

__global__ __launch_bounds__(256) void reduce4(
    const unsigned short* __restrict__ p0, const unsigned short* __restrict__ p1,
    const unsigned short* __restrict__ p2, const unsigned short* __restrict__ p3,
    const float* __restrict__ pl, unsigned short* __restrict__ ctx)
{
    const int i  = blockIdx.x * 256 + threadIdx.x;
    const int e0 = i * 8;
    const int t  = e0 >> 10;
    const int h  = (e0 & 1023) >> 6;
    const int b  = t >> 11, q = t & 2047;
    const size_t lb = ((size_t)b * NHEAD + h) * SEQ + q;
    const size_t lstep = (size_t)BATCH * NHEAD * SEQ;
    const float l = pl[lb] + pl[lb + lstep] + pl[lb + 2*lstep] + pl[lb + 3*lstep];
    const float inv = 1.f / l;
    uint4 a = ((const uint4*)p0)[i];
    uint4 b4 = ((const uint4*)p1)[i];
    uint4 c = ((const uint4*)p2)[i];
    uint4 d = ((const uint4*)p3)[i];
    uint4 r;
    r.x = addquad(a.x, b4.x, c.x, d.x, inv);
    r.y = addquad(a.y, b4.y, c.y, d.y, inv);
    r.z = addquad(a.z, b4.z, c.z, d.z, inv);
    r.w = addquad(a.w, b4.w, c.w, d.w, inv);
    ((uint4*)ctx)[i] = r;
}

// ---------------------------------------------------------------------------
extern "C" void kernel_launch(void* const* d_in, const int* in_sizes, int n_in,
                              void* d_out, int out_size, void* d_ws, size_t ws_size,
                              hipStream_t stream)
{
    const float* x  = (const float*)d_in[0];
    const float* wq = (const float*)d_in[1];
    const float* bq = (const float*)d_in[2];
    const float* wk = (const float*)d_in[3];
    const float* bk = (const float*)d_in[4];
    const float* wv = (const float*)d_in[5];
    const float* bv = (const float*)d_in[6];
    const float* wo = (const float*)d_in[7];
    const float* bo = (const float*)d_in[8];
    float* out = (float*)d_out;

    // ws layout (64 MB total)
    unsigned short* xb  = (unsigned short*)d_ws;       //  0- 8 MB  x bf16; then pO0
    unsigned short* wqb = xb  + (size_t)TOK * HID;     //  8-10 MB  wq; then pl (1 MB)
    unsigned short* wkb = wqb + (size_t)HID * HID;     // 10-12 MB
    unsigned short* wvb = wkb + (size_t)HID * HID;     // 12-14 MB
    unsigned short* wob = wvb + (size_t)HID * HID;     // 14-16 MB  (live to O-proj)
    unsigned short* qb  = wob + (size_t)HID * HID;     // 16-24 MB  Q; then ctx
    unsigned short* kb  = qb  + (size_t)TOK * HID;     // 24-32 MB  K
    unsigned short* vtb = kb  + (size_t)TOK * HID;     // 32-40 MB  V^T
    unsigned short* cb  = vtb + (size_t)TOK * HID;     // 40-48 MB  pO1
    unsigned short* cb2 = cb  + (size_t)TOK * HID;     // 48-56 MB  pO2
    unsigned short* cb3 = cb2 + (size_t)TOK * HID;     // 56-64 MB  pO3

    const dim3 blk(256);

    cvt_all<<<dim3(TOK*HID/8/256, 5), blk, 0, stream>>>(
        x, wq, wk, wv, wo, xb, wqb, wkb, wvb, wob, TOK*HID/8, HID*HID/8);

    // QKV: 128x128 tile, 768 blocks; MINW=4 -> 4 blocks/CU (VGPR 104 fits 128 cap)
    gemm_t<128, 128, 3, false, 4><<<dim3(HID/128, TOK/128, 3), blk, 0, stream>>>(
        xb, wqb, wkb, wvb, bq, bk, bv, qb, kb, vtb, TOK, HID, HID);

    // attention: 4-way key split, partials -> xb/cb/cb2/cb3, l -> wqb
    attn_v8<<<dim3(SEQ/256, NHEAD, BATCH*4), blk, 0, stream>>>(
        qb, kb, vtb, xb, cb, cb2, cb3, (float*)wqb);

    // recombine 4 partials -> ctx into qb (dead after attn)
    reduce4<<<dim3(TOK*HID/8/256), blk, 0, stream>>>(
        xb, cb, cb2, cb3, (float*)wqb, qb);

    // O-proj: 64x64 tile, 1024 blocks = 4/CU (was 512 = 2/CU)
    gemm_t<64, 64, 1, true, 4><<<dim3(HID/64, TOK/64, 1), blk, 0, stream>>>(
        qb, wob, wob, wob, bo, bo, bo, out, out, out, TOK, HID, HID);
}